// Round 1
// baseline (1702.988 us; speedup 1.0000x reference)
//
#include <hip/hip_runtime.h>
#include <math.h>

#define G_ZERO 0.5f

// ---------------------------------------------------------------------------
// Direct 3x3 conv, stride 1, pad 1, fp32.
//   in  : [256][C_IN][32][32]
//   w   : [128][C_IN][3][3]
//   bias: [128]
//   out : [256][128][32][32]
// Block: 256 threads computes one image x 16 output channels (full 32x32).
// Each thread: 16 oc x 4 horizontally-adjacent pixels in registers.
// ---------------------------------------------------------------------------
template<int C_IN>
__global__ __launch_bounds__(256, 2)
void conv3x3_kernel(const float* __restrict__ in,
                    const float* __restrict__ w,
                    const float* __restrict__ bias,
                    float* __restrict__ out)
{
    constexpr int OC_TILE = 16;
    constexpr int CHUNK   = 8;

    const int img = blockIdx.x >> 3;              // 0..255
    const int ocb = (blockIdx.x & 7) * OC_TILE;   // 0,16,...,112
    const int tid = threadIdx.x;

    // weights staged as [ic*9 + k][oc16] so 16 oc are contiguous
    __shared__ float w_s[C_IN * 9 * OC_TILE];
    // input chunk with halo; rows padded to 36 floats (144B, 16B-aligned rows)
    __shared__ float in_s[CHUNK][34][36];
    __shared__ float b_s[OC_TILE];

    for (int i = tid; i < C_IN * 9 * OC_TILE; i += 256) {
        int oc = i & (OC_TILE - 1);
        int kk = i >> 4;                          // ic*9 + k
        w_s[i] = w[(size_t)(ocb + oc) * (C_IN * 9) + kk];
    }
    if (tid < OC_TILE) b_s[tid] = bias[ocb + tid];

    const int r  = tid >> 3;          // output row 0..31
    const int x0 = (tid & 7) * 4;     // output col base 0,4,...,28

    float acc[OC_TILE][4];
    #pragma unroll
    for (int o = 0; o < OC_TILE; ++o)
        #pragma unroll
        for (int p = 0; p < 4; ++p) acc[o][p] = 0.f;

    const float* inb = in + (size_t)img * C_IN * 1024;

    for (int cb = 0; cb < C_IN; cb += CHUNK) {
        __syncthreads();   // previous compute done (and, first iter, w_s ready)
        // stage CHUNK channels with 1-px zero halo (cols 0..33 used)
        for (int i = tid; i < CHUNK * 34 * 34; i += 256) {
            int c   = i / (34 * 34);
            int rem = i - c * (34 * 34);
            int y   = rem / 34;
            int x   = rem - y * 34;
            int gy = y - 1, gx = x - 1;
            float v = 0.f;
            if ((unsigned)gy < 32u && (unsigned)gx < 32u)
                v = inb[(size_t)(cb + c) * 1024 + gy * 32 + gx];
            in_s[c][y][x] = v;
        }
        __syncthreads();

        #pragma unroll
        for (int ic = 0; ic < CHUNK; ++ic) {
            #pragma unroll
            for (int ky = 0; ky < 3; ++ky) {
                const float* row = &in_s[ic][r + ky][x0];
                float4 p03 = *(const float4*)(row);      // 16B aligned
                float2 p45 = *(const float2*)(row + 4);
                float px[6] = {p03.x, p03.y, p03.z, p03.w, p45.x, p45.y};
                const float* wrow = &w_s[((size_t)(cb + ic) * 9 + ky * 3) * OC_TILE];
                #pragma unroll
                for (int kx = 0; kx < 3; ++kx) {
                    const float* wp = wrow + kx * OC_TILE;
                    #pragma unroll
                    for (int og = 0; og < 4; ++og) {
                        float4 wv = *(const float4*)(wp + og * 4); // uniform -> broadcast
                        #pragma unroll
                        for (int j = 0; j < 4; ++j) {
                            float wj = (j == 0) ? wv.x : (j == 1) ? wv.y : (j == 2) ? wv.z : wv.w;
                            int oc = og * 4 + j;
                            #pragma unroll
                            for (int p = 0; p < 4; ++p)
                                acc[oc][p] = fmaf(wj, px[kx + p], acc[oc][p]);
                        }
                    }
                }
            }
        }
    }

    // epilogue: +bias, store float4
    float* ob = out + ((size_t)img * 128 + ocb) * 1024 + r * 32 + x0;
    #pragma unroll
    for (int o = 0; o < OC_TILE; ++o) {
        float bo = b_s[o];
        float4 v = make_float4(acc[o][0] + bo, acc[o][1] + bo,
                               acc[o][2] + bo, acc[o][3] + bo);
        *(float4*)(ob + (size_t)o * 1024) = v;
    }
}

// ---------------------------------------------------------------------------
// minGRU scan along S=64. gh: [B=4][S=64][128][1024] (gate ch 0..63,
// hidden ch 64..127). out: [B][S][64][1024]. hlast: [B][64][1024].
// One thread owns 2 adjacent hw positions (float2), prefetches t+1.
// ---------------------------------------------------------------------------
__global__ __launch_bounds__(256)
void scan_kernel(const float* __restrict__ gh,
                 float* __restrict__ out,
                 float* __restrict__ hlast)
{
    const int idx = blockIdx.x * 256 + threadIdx.x;  // over 4*64*512 pairs
    const int hw2 = idx & 511;
    const int c   = (idx >> 9) & 63;
    const int b   = idx >> 15;

    const size_t IMG = 128 * 1024;                   // gh per-t stride
    const float* gp = gh  + (size_t)b * 64 * IMG + (size_t)c * 1024 + hw2 * 2;
    const float* hp = gp + 64 * 1024;
    float*       op = out + (size_t)b * 64 * 65536 + (size_t)c * 1024 + hw2 * 2;

    float2 h = make_float2(G_ZERO, G_ZERO);
    float2 gt = *(const float2*)gp;
    float2 hd = *(const float2*)hp;

    for (int t = 0; t < 64; ++t) {
        float2 ngt, nhd;
        if (t < 63) {   // prefetch next step before transcendental math
            ngt = *(const float2*)(gp + (size_t)(t + 1) * IMG);
            nhd = *(const float2*)(hp + (size_t)(t + 1) * IMG);
        }
        float zx = 1.f / (1.f + __expf(-gt.x));
        float zy = 1.f / (1.f + __expf(-gt.y));
        float ggx = (hd.x >= 0.f) ? hd.x + 0.5f : 1.f / (1.f + __expf(-hd.x));
        float ggy = (hd.y >= 0.f) ? hd.y + 0.5f : 1.f / (1.f + __expf(-hd.y));
        h.x = (1.f - zx) * h.x + zx * ggx;
        h.y = (1.f - zy) * h.y + zy * ggy;
        *(float2*)(op + (size_t)t * 65536) = h;
        gt = ngt; hd = nhd;
    }
    *(float2*)(hlast + (size_t)b * 65536 + (size_t)c * 1024 + hw2 * 2) = h;
}

// ---------------------------------------------------------------------------
// out layout (flat floats): out2 [16777216] | h1 [262144] | h2 [262144]
// ws: gh buffer 256*128*1024 floats = 134 MB
// out1 (67 MB) is staged in d_out[0..16777216) and overwritten by out2 later.
// ---------------------------------------------------------------------------
extern "C" void kernel_launch(void* const* d_in, const int* in_sizes, int n_in,
                              void* d_out, int out_size, void* d_ws, size_t ws_size,
                              hipStream_t stream)
{
    const float* x  = (const float*)d_in[0];
    const float* w1 = (const float*)d_in[1];
    const float* b1 = (const float*)d_in[2];
    const float* w2 = (const float*)d_in[3];
    const float* b2 = (const float*)d_in[4];

    float* out  = (float*)d_out;
    float* gh   = (float*)d_ws;                  // 33,554,432 floats
    float* out1 = out;                           // staged in d_out (overwritten by out2)
    float* out2 = out;
    float* h1   = out + 16777216;
    float* h2   = h1 + 262144;

    // layer 1
    conv3x3_kernel<32><<<dim3(2048), dim3(256), 0, stream>>>(x, w1, b1, gh);
    scan_kernel<<<dim3(512), dim3(256), 0, stream>>>(gh, out1, h1);
    // layer 2 (reads out1 from d_out, reuses gh workspace)
    conv3x3_kernel<64><<<dim3(2048), dim3(256), 0, stream>>>(out1, w2, b2, gh);
    scan_kernel<<<dim3(512), dim3(256), 0, stream>>>(gh, out2, h2);
}

// Round 2
// 522.110 us; speedup vs baseline: 3.2617x; 3.2617x over previous
//
#include <hip/hip_runtime.h>
#include <math.h>
#include <stdint.h>

#define G_ZERO 0.5f

typedef _Float16 half8 __attribute__((ext_vector_type(8)));
typedef float f32x4 __attribute__((ext_vector_type(4)));

__device__ __host__ __forceinline__ int b_swz(int oc) {
    return (oc & 3) ^ ((oc >> 2) & 3);
}

// ---------------------------------------------------------------------------
// Weight repack: w fp32 [128][C][3][3] -> per-chunk swizzled f16 hi/lo images
// that byte-match the conv kernel's B LDS tile (chunk = (ky,kx,cslice), K=32).
// dst halfword index: tt*4096 + oc*32 + ((kloc>>3)^swz(oc))*8 + (kloc&7)
// ---------------------------------------------------------------------------
template<int C>
__global__ __launch_bounds__(256)
void repack_w(const float* __restrict__ w, uint16_t* __restrict__ whi,
              uint16_t* __restrict__ wlo)
{
    constexpr int nCs = C / 32;
    constexpr int nCh = 9 * nCs;
    int idx = blockIdx.x * 256 + threadIdx.x;
    if (idx >= nCh * 128 * 32) return;
    int kloc = idx & 31;
    int oc   = (idx >> 5) & 127;
    int tt   = idx >> 12;
    int kyx = tt / nCs, cs = tt % nCs;
    int ky = kyx / 3, kx = kyx % 3;
    int c = cs * 32 + kloc;
    float v = w[(size_t)oc * C * 9 + c * 9 + ky * 3 + kx];
    _Float16 hi = (_Float16)v;
    _Float16 lo = (_Float16)(v - (float)hi);
    int dst = tt * 4096 + oc * 32 + (((kloc >> 3) ^ b_swz(oc)) << 3) + (kloc & 7);
    whi[dst] = __builtin_bit_cast(uint16_t, hi);
    wlo[dst] = __builtin_bit_cast(uint16_t, lo);
}

// ---------------------------------------------------------------------------
// Implicit-GEMM conv3x3 via mfma_f32_16x16x32_f16, 3-pass hi/lo split.
// Block: 256 thr = 4 waves (2M x 2N), tile M=128 px (4 image rows) x N=128 oc.
// A LDS: [6 rows][34 cols][2C ch f16] (hi plane 0..C-1, lo plane C..2C-1),
//        channel-block XOR swizzle by column -> <=2-way bank conflicts.
// B LDS: 2 x 8KB chunk buffers (reg-staged double buffer).
// gh out: NHWC  ((img*1024 + y*32 + x)*128 + oc), fp32 + bias.
// ---------------------------------------------------------------------------
template<int C, bool NHWC_IN>
__global__ __launch_bounds__(256)
void conv_mfma(const float* __restrict__ in, const uint16_t* __restrict__ whi,
               const uint16_t* __restrict__ wlo, const float* __restrict__ bias,
               float* __restrict__ gh)
{
    constexpr int nCs = C / 32;
    constexpr int nCh = 9 * nCs;
    constexpr int T = 3 * nCh;                 // pass0 Ah*Bh, pass1 Ah*Bl, pass2 Al*Bh
    constexpr int CB = 2 * C;                  // channels incl. lo plane
    constexpr int CMASK = CB / 8 - 1;          // xor mask over 16B channel blocks
    constexpr int PIX_B = CB * 2;              // bytes per pixel in A tile
    constexpr int A_BYTES = 6 * 34 * PIX_B;

    __shared__ char smem[A_BYTES + 16384];

    const int tid = threadIdx.x;
    const int l = tid & 63;
    const int wv = tid >> 6;
    const int wv_m = wv >> 1, wv_n = wv & 1;
    const int g16 = l >> 4;
    const int ln15 = l & 15;
    const int img = blockIdx.x >> 3;
    const int y0 = (blockIdx.x & 7) * 4;

    // ---- zero halo columns 0 and 33 (full pixel each)
    for (int e = tid; e < 6 * 2 * (PIX_B / 4); e += 256) {
        int pj = e / (PIX_B / 4);
        int j  = e % (PIX_B / 4);
        int row = pj >> 1;
        int col = (pj & 1) ? 33 : 0;
        *(float*)(smem + (row * 34 + col) * PIX_B + j * 4) = 0.f;
    }
    // ---- stage A tile: rows y0-1..y0+4, cols 1..32, all C channels, hi+lo
    for (int e = tid; e < C * 192; e += 256) {
        int c, x, y6;
        if constexpr (NHWC_IN) { c = e & (C - 1); int r2 = e >> 6; x = r2 & 31; y6 = r2 >> 5; }
        else                   { x = e & 31; int r2 = e >> 5; y6 = r2 % 6; c = r2 / 6; }
        int gy = y0 - 1 + y6;
        float v = 0.f;
        if ((unsigned)gy < 32u) {
            if constexpr (NHWC_IN) v = in[((size_t)img * 1024 + gy * 32 + x) * C + c];
            else                   v = in[((size_t)img * C + c) * 1024 + gy * 32 + x];
        }
        _Float16 hi = (_Float16)v;
        _Float16 lo = (_Float16)(v - (float)hi);
        int col = x + 1;
        int slot = (c >> 3) ^ (col & CMASK);
        int addr = (y6 * 34 + col) * PIX_B + slot * 16 + (c & 7) * 2;
        *(uint16_t*)(smem + addr) = __builtin_bit_cast(uint16_t, hi);
        // lo plane: channel C+c -> slot ^= C/8 -> addr ^= 2C (pure xor, no carry)
        *(uint16_t*)(smem + (addr ^ (2 * C))) = __builtin_bit_cast(uint16_t, lo);
    }

    f32x4 acc[4][4];
    #pragma unroll
    for (int mf = 0; mf < 4; ++mf)
        #pragma unroll
        for (int nf = 0; nf < 4; ++nf) acc[mf][nf] = (f32x4)0.f;

    // ---- B-chunk staging helpers (register path, double buffer)
    auto stage_load = [&](int t, int4& r0, int4& r1) {
        int tt = t % nCh;
        const uint16_t* src = ((t / nCh) == 1) ? wlo : whi;
        const char* p = (const char*)src + (size_t)tt * 8192;
        r0 = *(const int4*)(p + tid * 16);
        r1 = *(const int4*)(p + 4096 + tid * 16);
    };
    auto stage_write = [&](int buf, const int4& r0, const int4& r1) {
        char* b = smem + A_BYTES + buf * 8192;
        *(int4*)(b + tid * 16) = r0;
        *(int4*)(b + 4096 + tid * 16) = r1;
    };

    int4 s0, s1;
    stage_load(0, s0, s1);
    stage_write(0, s0, s1);
    __syncthreads();   // A tile + B buf0 ready

    for (int t = 0; t < T; ++t) {
        if (t + 1 < T) stage_load(t + 1, s0, s1);   // global loads overlap MFMA

        int tt = t % nCh;
        int pass = t / nCh;
        int abase = (pass == 2) ? (C / 8) : 0;      // pass2 reads A lo plane
        int kyx = tt / nCs, cs = tt - kyx * nCs;
        int ky = kyx / 3, kx = kyx - ky * 3;
        char* bbuf = smem + A_BYTES + (t & 1) * 8192;

        half8 a[4], b[4];
        #pragma unroll
        for (int nf = 0; nf < 4; ++nf) {
            int oc = wv_n * 64 + nf * 16 + ln15;
            b[nf] = *(half8*)(bbuf + oc * 64 + ((g16 ^ b_swz(oc)) << 4));
        }
        #pragma unroll
        for (int mf = 0; mf < 4; ++mf) {
            int row = wv_m * 2 + (mf >> 1) + ky;
            int col = (mf & 1) * 16 + ln15 + kx;
            int cblk = abase + cs * 4 + g16;
            a[mf] = *(half8*)(smem + (row * 34 + col) * PIX_B
                              + ((cblk ^ (col & CMASK)) << 4));
        }
        #pragma unroll
        for (int mf = 0; mf < 4; ++mf)
            #pragma unroll
            for (int nf = 0; nf < 4; ++nf)
                acc[mf][nf] = __builtin_amdgcn_mfma_f32_16x16x32_f16(
                    a[mf], b[nf], acc[mf][nf], 0, 0, 0);

        if (t + 1 < T) stage_write((t + 1) & 1, s0, s1);
        __syncthreads();
    }

    // ---- epilogue: C/D layout col(oc)=lane&15, row(px)=(lane>>4)*4+reg (m89)
    #pragma unroll
    for (int mf = 0; mf < 4; ++mf) {
        int pbase = wv_m * 64 + mf * 16 + g16 * 4;
        #pragma unroll
        for (int nf = 0; nf < 4; ++nf) {
            int oc = wv_n * 64 + nf * 16 + ln15;
            float bv = bias[oc];
            #pragma unroll
            for (int r = 0; r < 4; ++r) {
                int pp = pbase + r;
                int y = y0 + (pp >> 5), x = pp & 31;
                gh[((size_t)img * 1024 + y * 32 + x) * 128 + oc] = acc[mf][nf][r] + bv;
            }
        }
    }
}

// ---------------------------------------------------------------------------
// scan1: gh NHWC [img][1024][128] -> out1 NHWC [img][1024][64], h1 NCHW.
// thread = (b, hw, cg); fully coalesced reads/writes (cg fastest).
// ---------------------------------------------------------------------------
__global__ __launch_bounds__(256)
void scan_nhwc(const float* __restrict__ gh, float* __restrict__ out1,
               float* __restrict__ h1)
{
    int idx = blockIdx.x * 256 + threadIdx.x;   // 262144 total
    int cg = idx & 63;
    int hw = (idx >> 6) & 1023;
    int b  = idx >> 16;
    const float* gp = gh + ((size_t)(b * 64) * 1024 + hw) * 128 + cg;
    float* op = out1 + ((size_t)(b * 64) * 1024 + hw) * 64 + cg;
    float h = G_ZERO;
    for (int s = 0; s < 64; ++s) {
        float gate = gp[(size_t)s * 131072];
        float hid  = gp[(size_t)s * 131072 + 64];
        float z  = 1.f / (1.f + __expf(-gate));
        float gv = (hid >= 0.f) ? hid + 0.5f : 1.f / (1.f + __expf(-hid));
        h = (1.f - z) * h + z * gv;
        op[(size_t)s * 65536] = h;
    }
    h1[(size_t)(b * 64 + cg) * 1024 + hw] = h;
}

// ---------------------------------------------------------------------------
// scan2: gh NHWC -> out2 NCHW (B,S,64,H,W) + h2 NCHW, LDS bounce for the
// c<->hw transpose on the store side. block = (b, 16-px tile), 256 thr.
// ---------------------------------------------------------------------------
__global__ __launch_bounds__(256)
void scan_nchw(const float* __restrict__ gh, float* __restrict__ out2,
               float* __restrict__ h2)
{
    __shared__ float sh2[16][65];
    int tid = threadIdx.x;
    int b   = blockIdx.x >> 6;
    int hw0 = (blockIdx.x & 63) * 16;
    int cg = tid & 63, pq = tid >> 6;          // compute mapping (cg fastest)
    int opx = tid & 15, ocq = tid >> 4;        // store mapping (px fastest)
    float h[4] = {G_ZERO, G_ZERO, G_ZERO, G_ZERO};
    for (int s = 0; s < 64; ++s) {
        size_t ib = (size_t)(b * 64 + s) * 1024 + hw0;
        #pragma unroll
        for (int i = 0; i < 4; ++i) {
            int px = pq * 4 + i;
            float gate = gh[(ib + px) * 128 + cg];
            float hid  = gh[(ib + px) * 128 + 64 + cg];
            float z  = 1.f / (1.f + __expf(-gate));
            float gv = (hid >= 0.f) ? hid + 0.5f : 1.f / (1.f + __expf(-hid));
            h[i] = (1.f - z) * h[i] + z * gv;
            sh2[px][cg] = h[i];
        }
        __syncthreads();
        #pragma unroll
        for (int i = 0; i < 4; ++i) {
            int c2 = ocq * 4 + i;
            float v = sh2[opx][c2];
            out2[((size_t)(b * 64 + s) * 64 + c2) * 1024 + hw0 + opx] = v;
            if (s == 63)
                h2[(size_t)(b * 64 + c2) * 1024 + hw0 + opx] = v;
        }
        __syncthreads();
    }
}

// ---------------------------------------------------------------------------
// d_out floats: out2 [16777216] | h1 [262144] | h2 [262144]
// ws: gh (33554432 floats = 134 MB).  Weight hi/lo buffers live in the h1/h2
// regions until their consumers finish, then get overwritten by real h1/h2.
// out1 (NHWC scratch) lives in the out2 region until scan2 overwrites it.
// ---------------------------------------------------------------------------
extern "C" void kernel_launch(void* const* d_in, const int* in_sizes, int n_in,
                              void* d_out, int out_size, void* d_ws, size_t ws_size,
                              hipStream_t stream)
{
    const float* x  = (const float*)d_in[0];
    const float* w1 = (const float*)d_in[1];
    const float* b1 = (const float*)d_in[2];
    const float* w2 = (const float*)d_in[3];
    const float* b2 = (const float*)d_in[4];

    float* out  = (float*)d_out;
    float* gh   = (float*)d_ws;
    float* out1 = out;                          // NHWC scratch in out2 region
    float* h1   = out + 16777216;
    float* h2   = out + 17039360;

    uint16_t* w1hi = (uint16_t*)h1;             // 9*4096 halfs
    uint16_t* w1lo = w1hi + 36864;
    uint16_t* w2hi = (uint16_t*)h2;             // 18*4096 halfs
    uint16_t* w2lo = w2hi + 73728;

    repack_w<32><<<144, 256, 0, stream>>>(w1, w1hi, w1lo);
    repack_w<64><<<288, 256, 0, stream>>>(w2, w2hi, w2lo);

    conv_mfma<32, false><<<2048, 256, 0, stream>>>(x, w1hi, w1lo, b1, gh);
    scan_nhwc<<<1024, 256, 0, stream>>>(gh, out1, h1);
    conv_mfma<64, true><<<2048, 256, 0, stream>>>(out1, w2hi, w2lo, b2, gh);
    scan_nchw<<<256, 256, 0, stream>>>(gh, out, h2);
}